// Round 3
// baseline (4884.990 us; speedup 1.0000x reference)
//
#include <hip/hip_runtime.h>
#include <math.h>

#define N_NODES 20000
#define N_EDGES 320000
#define F_IN 128
#define C 300
#define L_STEPS 8
#define KP 320                 // padded K (multiple of 32)
#define SP 328                 // LDS row stride (fp16 elems)
#define NPAD 304               // padded gate-col dim (19*16)
#define GOFS 97280             // 40*NPAD*8, per-gate block in swizzled weights
#define WSTEP 291840           // 3*GOFS, per (layer,step)
#define LOSCALE 2048.0f        // lo-part pre-scale (2^11), avoids fp16 denormals
#define LBH 12288              // halfs per B LDS buffer (24 KB)

typedef _Float16 half8 __attribute__((ext_vector_type(8)));
typedef _Float16 half4 __attribute__((ext_vector_type(4)));
typedef __attribute__((ext_vector_type(4))) float floatx4;

__device__ __forceinline__ void split16(float x, _Float16& hi, _Float16& lo) {
    hi = (_Float16)x;
    lo = (_Float16)((x - (float)hi) * LOSCALE);
}

// ---------------- pad x -> h (fp32) + hh/hl (fp16 split, stride KP) --------
__global__ void pad_kernel(const float* __restrict__ x, float* __restrict__ h,
                           _Float16* __restrict__ hh, _Float16* __restrict__ hl) {
    int idx = blockIdx.x * blockDim.x + threadIdx.x;
    if (idx >= N_NODES * KP) return;
    int n = idx / KP, c = idx - n * KP;
    float v = (c < F_IN) ? x[n * F_IN + c] : 0.0f;
    if (c < C) h[(size_t)n * C + c] = v;
    _Float16 hi, lo; split16(v, hi, lo);
    hh[idx] = hi; hl[idx] = lo;
}

// ---------------- CSR build (verified round 4) ----------------
__global__ void hist_kernel(const int* __restrict__ dst, int* __restrict__ deg) {
    int e = blockIdx.x * blockDim.x + threadIdx.x;
    if (e < N_EDGES) atomicAdd(&deg[dst[e]], 1);
}

__global__ void scan_kernel(const int* __restrict__ deg, int* __restrict__ row_ptr) {
    __shared__ int part[1024];
    const int PER = 20;
    int t = threadIdx.x;
    int base = t * PER;
    int vals[PER];
    int s = 0;
    #pragma unroll
    for (int i = 0; i < PER; ++i) {
        int idx = base + i;
        int v = (idx < N_NODES) ? deg[idx] : 0;
        vals[i] = s; s += v;
    }
    part[t] = s;
    __syncthreads();
    for (int off = 1; off < 1024; off <<= 1) {
        int v = (t >= off) ? part[t - off] : 0;
        __syncthreads();
        part[t] += v;
        __syncthreads();
    }
    int pre = (t == 0) ? 0 : part[t - 1];
    #pragma unroll
    for (int i = 0; i < PER; ++i) {
        int idx = base + i;
        if (idx < N_NODES) row_ptr[idx] = pre + vals[i];
    }
    if (t == 0) row_ptr[N_NODES] = N_EDGES;
}

__global__ void cursor_copy(const int* __restrict__ row_ptr, int* __restrict__ cur) {
    int i = blockIdx.x * blockDim.x + threadIdx.x;
    if (i < N_NODES) cur[i] = row_ptr[i];
}

__global__ void fill_kernel(const int* __restrict__ src, const int* __restrict__ dst,
                            int* __restrict__ cur, int* __restrict__ colx) {
    int e = blockIdx.x * blockDim.x + threadIdx.x;
    if (e >= N_EDGES) return;
    int d = dst[e];
    int p = atomicAdd(&cur[d], 1);
    colx[p] = src[e];
}

// ---- WcombT[r][gn] = sum_c W[r][c]*wih[gn][c]; swizzled fp16 hi/lo --------
__launch_bounds__(256)
__global__ void wcomb_split(const float* __restrict__ W1, const float* __restrict__ W2,
                            const float* __restrict__ wih1, const float* __restrict__ wih2,
                            _Float16* __restrict__ whi, _Float16* __restrict__ wlo) {
    int z = blockIdx.z, layer = z >> 3, step = z & 7;
    const float* A  = (layer ? W2 : W1) + (size_t)step * C * C;  // [r][c]
    const float* Bm = layer ? wih2 : wih1;                       // [gn][c]
    _Float16* ohi = whi + (size_t)z * WSTEP;
    _Float16* olo = wlo + (size_t)z * WSTEP;
    __shared__ float As[16][68];
    __shared__ float Bs[16][68];
    int tid = threadIdx.x;
    int tx = tid & 15, ty = tid >> 4;
    int rowBase = blockIdx.y * 64, colBase = blockIdx.x * 64;
    float acc[4][4] = {};
    int lr = tid >> 2, k4 = (tid & 3) * 4;
    for (int k0 = 0; k0 < C; k0 += 16) {
        {
            int gr = rowBase + lr;
            int gn = colBase + lr;
            #pragma unroll
            for (int j = 0; j < 4; ++j) {
                int k = k0 + k4 + j;
                As[k4 + j][lr] = (gr < C && k < C) ? A[(size_t)gr * C + k] : 0.f;
                Bs[k4 + j][lr] = (gn < 3 * C && k < C) ? Bm[(size_t)gn * C + k] : 0.f;
            }
        }
        __syncthreads();
        #pragma unroll
        for (int k = 0; k < 16; ++k) {
            float4 a = *(const float4*)&As[k][ty * 4];
            float4 b = *(const float4*)&Bs[k][tx * 4];
            float av[4] = {a.x, a.y, a.z, a.w};
            float bv[4] = {b.x, b.y, b.z, b.w};
            #pragma unroll
            for (int i = 0; i < 4; ++i)
                #pragma unroll
                for (int j = 0; j < 4; ++j)
                    acc[i][j] += av[i] * bv[j];
        }
        __syncthreads();
    }
    #pragma unroll
    for (int i = 0; i < 4; ++i) {
        int r = rowBase + ty * 4 + i;
        if (r >= C) continue;
        #pragma unroll
        for (int j = 0; j < 4; ++j) {
            int gn = colBase + tx * 4 + j;
            if (gn >= 3 * C) continue;
            int g = (gn >= 2 * C) ? 2 : ((gn >= C) ? 1 : 0);
            int n = gn - g * C;
            size_t idx = (((size_t)g * 40 + (r >> 3)) * NPAD + n) * 8 + (r & 7);
            _Float16 hi, lo; split16(acc[i][j], hi, lo);
            ohi[idx] = hi; olo[idx] = lo;
        }
    }
}

// ---- whh^T swizzle + split: B[k][gn] = whh[gn][k], fp16 hi/lo ----
__global__ void whh_split(const float* __restrict__ whh1, const float* __restrict__ whh2,
                          _Float16* __restrict__ whi, _Float16* __restrict__ wlo) {
    int idx = blockIdx.x * blockDim.x + threadIdx.x;
    if (idx >= 2 * 3 * C * C) return;
    int k = idx % C;
    int rest = idx / C;
    int gn = rest % (3 * C);
    int layer = rest / (3 * C);
    int g = (gn >= 2 * C) ? 2 : ((gn >= C) ? 1 : 0);
    int n = gn - g * C;
    float v = (layer ? whh2 : whh1)[(size_t)gn * C + k];
    size_t o = (size_t)layer * WSTEP + (((size_t)g * 40 + (k >> 3)) * NPAD + n) * 8 + (k & 7);
    _Float16 hi, lo; split16(v, hi, lo);
    whi[o] = hi; wlo[o] = lo;
}

// ---- CSR gather from fp32 h -> exact fp16 hi/lo split agg [N x KP] ----
__global__ void aggregate_kernel(const float* __restrict__ h,
                                 const int* __restrict__ rowp,
                                 const int* __restrict__ colx,
                                 _Float16* __restrict__ agh, _Float16* __restrict__ agl) {
    const int node = blockIdx.x * 4 + (threadIdx.x >> 6);
    const int lane = threadIdx.x & 63;
    const int beg = rowp[node], end = rowp[node + 1];
    float4 a0 = make_float4(0.f, 0.f, 0.f, 0.f);
    float4 a1 = make_float4(0.f, 0.f, 0.f, 0.f);
    const bool tail = lane < 11;       // chunks 64..74 cover cols 256..299
    for (int e = beg; e < end; ++e) {
        const float* row = h + (size_t)colx[e] * C;
        float4 v = *(const float4*)&row[lane * 4];
        a0.x += v.x; a0.y += v.y; a0.z += v.z; a0.w += v.w;
        if (tail) {
            float4 u = *(const float4*)&row[(64 + lane) * 4];
            a1.x += u.x; a1.y += u.y; a1.z += u.z; a1.w += u.w;
        }
    }
    half4 vh, vl;
    {
        _Float16 hi, lo;
        split16(a0.x, hi, lo); vh[0] = hi; vl[0] = lo;
        split16(a0.y, hi, lo); vh[1] = hi; vl[1] = lo;
        split16(a0.z, hi, lo); vh[2] = hi; vl[2] = lo;
        split16(a0.w, hi, lo); vh[3] = hi; vl[3] = lo;
    }
    _Float16* oh = agh + (size_t)node * KP;
    _Float16* ol = agl + (size_t)node * KP;
    *(half4*)&oh[lane * 4] = vh;
    *(half4*)&ol[lane * 4] = vl;
    if (tail) {
        _Float16 hi, lo;
        split16(a1.x, hi, lo); vh[0] = hi; vl[0] = lo;
        split16(a1.y, hi, lo); vh[1] = hi; vl[1] = lo;
        split16(a1.z, hi, lo); vh[2] = hi; vl[2] = lo;
        split16(a1.w, hi, lo); vh[3] = hi; vl[3] = lo;
        *(half4*)&oh[(64 + lane) * 4] = vh;
        *(half4*)&ol[(64 + lane) * 4] = vl;
    }
}

// 3 MFMAs per logical product: a1 += XH*BH; a2 += XH*BL + XL*BH
#define MFMA_TRIPLE(A1, A2, XH, XL, BH, BL)                                   \
    A1 = __builtin_amdgcn_mfma_f32_16x16x32_f16(XH, BH, A1, 0, 0, 0);         \
    A2 = __builtin_amdgcn_mfma_f32_16x16x32_f16(XH, BL, A2, 0, 0, 0);         \
    A2 = __builtin_amdgcn_mfma_f32_16x16x32_f16(XL, BH, A2, 0, 0, 0);

// ---- fused MFMA GRU step, v4: block-shared B via async LDS staging ----
// 512 threads = 8 waves (rw 0..3 row-subtile x cn 0..1 ct-column), M=64 rows.
// Per kt the block stages the 2-ct weight tile (24 KB, 12 mats x 4 kc x 32
// cols) into a double-buffered LDS region with global_load_lds (3 per
// thread), synchronized with counted vmcnt(3) + RAW s_barrier (syncthreads
// would drain vmcnt(0) and kill the pipeline - m97 lesson). Weight L2
// traffic drops 2.3x (read once per block, not once per wave). The agg
// (G) fragments live in registers (80 VGPR, loaded once, reused over all
// 10 ct-pairs) - the per-kt global A-stream is gone. hh/hl stay in LDS.
// Reg budget: acc 48 + G 80 + B frags 48 + misc ~25 = ~200 <= 256 (2/SIMD).
// ct pair (18,19): ghost ct=19 clamps to 18 (duplicate MFMA work) and the
// cn=1 wave SKIPS the epilogue to avoid a read-modify-write race.
__launch_bounds__(512, 2)
__global__ void gru_f16(_Float16* __restrict__ hh, _Float16* __restrict__ hl,
                        const _Float16* __restrict__ agh, const _Float16* __restrict__ agl,
                        const _Float16* __restrict__ wch, const _Float16* __restrict__ wcl,
                        const _Float16* __restrict__ whh_, const _Float16* __restrict__ whl_,
                        const float* __restrict__ bih, const float* __restrict__ bhh,
                        float* __restrict__ h) {
    __shared__ _Float16 Lhh[64 * SP];
    __shared__ _Float16 Lhl[64 * SP];
    __shared__ _Float16 LB[2 * LBH];
    const int tid = threadIdx.x;
    const int rowBase = blockIdx.x * 64;       // 313 blocks; last is partial
    // ---- stage hh/hl (64 rows, row-clamped) ----
    {
        int r = tid >> 3, c8 = tid & 7;
        int gr = rowBase + r; if (gr > N_NODES - 1) gr = N_NODES - 1;
        const _Float16* ph = hh + (size_t)gr * KP;
        const _Float16* pl = hl + (size_t)gr * KP;
        #pragma unroll
        for (int i = 0; i < 5; ++i) {
            int k = (c8 + i * 8) * 8;
            *(int4*)&Lhh[r * SP + k] = *(const int4*)&ph[k];
            *(int4*)&Lhl[r * SP + k] = *(const int4*)&pl[k];
        }
    }
    const int lane = tid & 63, w = tid >> 6;
    const int quad = lane >> 4, n15 = lane & 15;
    const int rw = w & 3, cnw = w >> 2;
    const int arow = rw * 16 + n15;
    // ---- G (agg hi/lo) fragments in registers: 16 rows, all 10 kt ----
    half8 gh_[10], gl_[10];
    {
        int gr = rowBase + arow; if (gr > N_NODES - 1) gr = N_NODES - 1;
        const _Float16* pg = agh + (size_t)gr * KP + quad * 8;
        const _Float16* pl2 = agl + (size_t)gr * KP + quad * 8;
        #pragma unroll
        for (int kt = 0; kt < 10; ++kt) {
            gh_[kt] = *(const half8*)&pg[kt * 32];
            gl_[kt] = *(const half8*)&pl2[kt * 32];
        }
    }
    // ---- stage-slot precompute: slot s = tid + i*512 ->
    //      s = ((cn*12 + mat)*4 + kc)*16 + n15  (half ofs s*8, lane-linear)
    const _Float16* gbs[3];
    int kcs[3], n15s[3], cns[3];
    #pragma unroll
    for (int i = 0; i < 3; ++i) {
        int s = tid + i * 512;
        n15s[i] = s & 15;
        kcs[i] = (s >> 4) & 3;
        int mc = s >> 6;                     // 0..23
        int mat = (mc >= 12) ? (mc - 12) : mc;
        cns[i] = (mc >= 12) ? 1 : 0;
        int arrs = mat / 3, gate = mat - arrs * 3;
        const _Float16* base = (arrs == 0) ? wch : (arrs == 1) ? wcl
                             : (arrs == 2) ? whh_ : whl_;
        gbs[i] = base + (size_t)gate * GOFS;
    }
    _Float16* ldsb = &LB[w * 512];           // + buf*LBH + i*4096 (+ lane*8 by HW)
    auto STAGE = [&](int c2, int kt2, int buf) {
        #pragma unroll
        for (int i = 0; i < 3; ++i) {
            int ct = c2 * 2 + cns[i]; if (ct > 18) ct = 18;
            int col = ct * 16 + n15s[i];
            const _Float16* src = gbs[i] + ((size_t)((kt2 * 4 + kcs[i]) * NPAD + col)) * 8;
            __builtin_amdgcn_global_load_lds(
                (const __attribute__((address_space(1))) void*)src,
                (__attribute__((address_space(3))) void*)(ldsb + buf * LBH + i * 4096),
                16, 0, 0);
        }
    };
    STAGE(0, 0, 0);
    __syncthreads();                          // drains prologue (once, fine)
    const _Float16* bb = &LB[cnw * 6144 + quad * 128 + n15 * 8];
    const int aofs = arow * SP + quad * 8;

    for (int c = 0; c < 10; ++c) {
        floatx4 a1[6], a2[6];
        #pragma unroll
        for (int g = 0; g < 6; ++g) {
            a1[g] = (floatx4){0.f, 0.f, 0.f, 0.f};
            a2[g] = (floatx4){0.f, 0.f, 0.f, 0.f};
        }
        #pragma unroll
        for (int kt = 0; kt < 10; ++kt) {
            if (kt < 9)      STAGE(c, kt + 1, (kt + 1) & 1);
            else if (c < 9)  STAGE(c + 1, 0, 0);
            __builtin_amdgcn_sched_barrier(0);
            if (kt == 9 && c == 9) { asm volatile("s_waitcnt vmcnt(0)" ::: "memory"); }
            else                   { asm volatile("s_waitcnt vmcnt(3)" ::: "memory"); }
            __builtin_amdgcn_s_barrier();     // buf[kt&1] fully staged
            const _Float16* bbk = bb + (kt & 1) * LBH;
            half8 b0  = *(const half8*)&bbk[0 * 512];
            half8 b1  = *(const half8*)&bbk[1 * 512];
            half8 b2  = *(const half8*)&bbk[2 * 512];
            half8 b3  = *(const half8*)&bbk[3 * 512];
            half8 b4  = *(const half8*)&bbk[4 * 512];
            half8 b5  = *(const half8*)&bbk[5 * 512];
            half8 b6  = *(const half8*)&bbk[6 * 512];
            half8 b7  = *(const half8*)&bbk[7 * 512];
            half8 b8  = *(const half8*)&bbk[8 * 512];
            half8 b9  = *(const half8*)&bbk[9 * 512];
            half8 b10 = *(const half8*)&bbk[10 * 512];
            half8 b11 = *(const half8*)&bbk[11 * 512];
            half8 AH = *(const half8*)&Lhh[aofs + kt * 32];
            half8 AL = *(const half8*)&Lhl[aofs + kt * 32];
            const half8 GH = gh_[kt], GL = gl_[kt];
            __builtin_amdgcn_s_setprio(1);
            MFMA_TRIPLE(a1[0], a2[0], GH, GL, b0, b3)
            MFMA_TRIPLE(a1[1], a2[1], GH, GL, b1, b4)
            MFMA_TRIPLE(a1[2], a2[2], GH, GL, b2, b5)
            MFMA_TRIPLE(a1[3], a2[3], AH, AL, b6, b9)
            MFMA_TRIPLE(a1[4], a2[4], AH, AL, b7, b10)
            MFMA_TRIPLE(a1[5], a2[5], AH, AL, b8, b11)
            __builtin_amdgcn_s_setprio(0);
            __builtin_amdgcn_s_barrier();     // all reads of buf[kt&1] done
        }
        // ---- epilogue for this ct (skip ghost ct=19 duplicate) ----
        const int ct = c * 2 + cnw;
        if (ct <= 18) {
            const int col = ct * 16 + n15;
            if (col < C) {
                const float invS = 1.0f / LOSCALE;
                const float br = bih[col], bz = bih[C + col], bn = bih[2 * C + col];
                const float cr = bhh[col], cz = bhh[C + col], cq = bhh[2 * C + col];
                #pragma unroll
                for (int i = 0; i < 4; ++i) {
                    int grow = rowBase + rw * 16 + quad * 4 + i;
                    if (grow < N_NODES) {
                        float ir  = a1[0][i] + a2[0][i] * invS + br;
                        float iz  = a1[1][i] + a2[1][i] * invS + bz;
                        float inn = a1[2][i] + a2[2][i] * invS + bn;
                        float hr  = a1[3][i] + a2[3][i] * invS + cr;
                        float hz  = a1[4][i] + a2[4][i] * invS + cz;
                        float hn  = a1[5][i] + a2[5][i] * invS + cq;
                        float r = 1.f / (1.f + __expf(-(ir + hr)));
                        float z = 1.f / (1.f + __expf(-(iz + hz)));
                        float nn = tanhf(inn + r * hn);
                        float hold = h[(size_t)grow * C + col];
                        float hnew = (1.f - z) * nn + z * hold;
                        h[(size_t)grow * C + col] = hnew;
                        _Float16 nh, nl; split16(hnew, nh, nl);
                        hh[(size_t)grow * KP + col] = nh;
                        hl[(size_t)grow * KP + col] = nl;
                    }
                }
            }
        }
    }
}

// ---------------- relu (h fp32 + hh/hl fp16) ----------------
__global__ void relu_kernel(float* __restrict__ h, _Float16* __restrict__ hh,
                            _Float16* __restrict__ hl) {
    int idx = blockIdx.x * blockDim.x + threadIdx.x;
    if (idx >= N_NODES * C) return;
    int n = idx / C, c = idx - n * C;
    float v = fmaxf(h[idx], 0.f);
    h[idx] = v;
    _Float16 hi, lo; split16(v, hi, lo);
    hh[(size_t)n * KP + c] = hi;
    hl[(size_t)n * KP + c] = lo;
}

// ---------------- mean pool ----------------
__global__ void pool_kernel(const float* __restrict__ h, float* __restrict__ pooled) {
    int c = threadIdx.x;
    if (c >= C) return;
    float acc = 0.f;
    for (int n = blockIdx.x; n < N_NODES; n += gridDim.x)
        acc += h[(size_t)n * C + c];
    atomicAdd(&pooled[c], acc);
}

// ---------------- log_softmax ----------------
__global__ void lsm_kernel(const float* __restrict__ pooled, float* __restrict__ out) {
    __shared__ float sm[512];
    int t = threadIdx.x;
    float v = (t < C) ? pooled[t] * (1.0f / N_NODES) : -INFINITY;
    sm[t] = v;
    __syncthreads();
    for (int s = 256; s > 0; s >>= 1) {
        if (t < s) sm[t] = fmaxf(sm[t], sm[t + s]);
        __syncthreads();
    }
    float mx = sm[0];
    __syncthreads();
    float e = (t < C) ? expf(v - mx) : 0.f;
    sm[t] = e;
    __syncthreads();
    for (int s = 256; s > 0; s >>= 1) {
        if (t < s) sm[t] += sm[t + s];
        __syncthreads();
    }
    float lse = logf(sm[0]);
    if (t < C) out[t] = (v - mx) - lse;
}

extern "C" void kernel_launch(void* const* d_in, const int* in_sizes, int n_in,
                              void* d_out, int out_size, void* d_ws, size_t ws_size,
                              hipStream_t stream) {
    const float* x      = (const float*)d_in[0];
    const int*   ei     = (const int*)d_in[1];
    const int*   src    = ei;
    const int*   dst    = ei + N_EDGES;
    const float* W1     = (const float*)d_in[2];
    const float* g1_wih = (const float*)d_in[3];
    const float* g1_whh = (const float*)d_in[4];
    const float* g1_bih = (const float*)d_in[5];
    const float* g1_bhh = (const float*)d_in[6];
    const float* W2     = (const float*)d_in[7];
    const float* g2_wih = (const float*)d_in[8];
    const float* g2_whh = (const float*)d_in[9];
    const float* g2_bih = (const float*)d_in[10];
    const float* g2_bhh = (const float*)d_in[11];

    char* p = (char*)d_ws;
    float* h = (float*)p;               p += (size_t)N_NODES * C * 4;    // 24.0 MB
    _Float16* hh = (_Float16*)p;        p += (size_t)N_NODES * KP * 2;   // 12.8 MB
    _Float16* hl = (_Float16*)p;        p += (size_t)N_NODES * KP * 2;   // 12.8 MB
    _Float16* agh = (_Float16*)p;       p += (size_t)N_NODES * KP * 2;   // 12.8 MB
    _Float16* agl = (_Float16*)p;       p += (size_t)N_NODES * KP * 2;   // 12.8 MB
    _Float16* wch = (_Float16*)p;       p += (size_t)16 * WSTEP * 2;     //  9.34 MB
    _Float16* wcl = (_Float16*)p;       p += (size_t)16 * WSTEP * 2;     //  9.34 MB
    _Float16* wh_hi = (_Float16*)p;     p += (size_t)2 * WSTEP * 2;      //  1.17 MB
    _Float16* wh_lo = (_Float16*)p;     p += (size_t)2 * WSTEP * 2;      //  1.17 MB
    float* pooled = (float*)p;          p += 1216;
    int* row_ptr = (int*)p;             p += 80016;
    int* colx = (int*)p;                p += (size_t)N_EDGES * 4;        //  1.28 MB
    int* deg = (int*)p;                 p += 80000;
    int* cursor = (int*)p;              p += 80000;

    hipMemsetAsync(deg, 0, N_NODES * sizeof(int), stream);
    hipMemsetAsync(agh, 0, (size_t)N_NODES * KP * 2, stream);
    hipMemsetAsync(agl, 0, (size_t)N_NODES * KP * 2, stream);
    hipMemsetAsync(wch, 0, (size_t)16 * WSTEP * 2, stream);
    hipMemsetAsync(wcl, 0, (size_t)16 * WSTEP * 2, stream);
    hipMemsetAsync(wh_hi, 0, (size_t)2 * WSTEP * 2, stream);
    hipMemsetAsync(wh_lo, 0, (size_t)2 * WSTEP * 2, stream);
    hipMemsetAsync(pooled, 0, C * sizeof(float), stream);

    pad_kernel<<<(N_NODES * KP + 255) / 256, 256, 0, stream>>>(x, h, hh, hl);

    hist_kernel<<<(N_EDGES + 255) / 256, 256, 0, stream>>>(dst, deg);
    scan_kernel<<<1, 1024, 0, stream>>>(deg, row_ptr);
    cursor_copy<<<(N_NODES + 255) / 256, 256, 0, stream>>>(row_ptr, cursor);
    fill_kernel<<<(N_EDGES + 255) / 256, 256, 0, stream>>>(src, dst, cursor, colx);

    wcomb_split<<<dim3(15, 5, 16), 256, 0, stream>>>(W1, W2, g1_wih, g2_wih, wch, wcl);
    whh_split<<<(2 * 3 * C * C + 255) / 256, 256, 0, stream>>>(g1_whh, g2_whh, wh_hi, wh_lo);

    for (int layer = 0; layer < 2; ++layer) {
        const float* bih = layer ? g2_bih : g1_bih;
        const float* bhh = layer ? g2_bhh : g1_bhh;
        const _Float16* whh_hi = wh_hi + (size_t)layer * WSTEP;
        const _Float16* whh_lo = wh_lo + (size_t)layer * WSTEP;
        for (int step = 0; step < L_STEPS; ++step) {
            const _Float16* wc_hi = wch + (size_t)(layer * 8 + step) * WSTEP;
            const _Float16* wc_lo = wcl + (size_t)(layer * 8 + step) * WSTEP;
            aggregate_kernel<<<N_NODES / 4, 256, 0, stream>>>(h, row_ptr, colx, agh, agl);
            gru_f16<<<(N_NODES + 63) / 64, 512, 0, stream>>>(
                hh, hl, agh, agl, wc_hi, wc_lo, whh_hi, whh_lo, bih, bhh, h);
        }
        if (layer == 0)
            relu_kernel<<<(N_NODES * C + 255) / 256, 256, 0, stream>>>(h, hh, hl);
    }

    pool_kernel<<<256, 320, 0, stream>>>(h, pooled);
    lsm_kernel<<<1, 512, 0, stream>>>(pooled, (float*)d_out);
}

// Round 5
// 4318.530 us; speedup vs baseline: 1.1312x; 1.1312x over previous
//
#include <hip/hip_runtime.h>
#include <math.h>

#define N_NODES 20000
#define N_EDGES 320000
#define F_IN 128
#define C 300
#define L_STEPS 8
#define KP 320                 // padded K (multiple of 32)
#define SP 328                 // LDS row stride (fp16 elems)
#define NPAD 304               // padded gate-col dim (19*16)
#define GOFS 97280             // 40*NPAD*8, per-gate block in swizzled weights
#define WSTEP 291840           // 3*GOFS, per (layer,step)
#define LOSCALE 2048.0f        // lo-part pre-scale (2^11), avoids fp16 denormals
#define LBH 12288              // halfs per B LDS buffer (24 KB)

typedef _Float16 half8 __attribute__((ext_vector_type(8)));
typedef _Float16 half4 __attribute__((ext_vector_type(4)));
typedef __attribute__((ext_vector_type(4))) float floatx4;

__device__ __forceinline__ void split16(float x, _Float16& hi, _Float16& lo) {
    hi = (_Float16)x;
    lo = (_Float16)((x - (float)hi) * LOSCALE);
}

// ---------------- pad x -> h (fp32) + hh/hl (fp16 split, stride KP) --------
__global__ void pad_kernel(const float* __restrict__ x, float* __restrict__ h,
                           _Float16* __restrict__ hh, _Float16* __restrict__ hl) {
    int idx = blockIdx.x * blockDim.x + threadIdx.x;
    if (idx >= N_NODES * KP) return;
    int n = idx / KP, c = idx - n * KP;
    float v = (c < F_IN) ? x[n * F_IN + c] : 0.0f;
    if (c < C) h[(size_t)n * C + c] = v;
    _Float16 hi, lo; split16(v, hi, lo);
    hh[idx] = hi; hl[idx] = lo;
}

// ---------------- CSR build (verified round 4) ----------------
__global__ void hist_kernel(const int* __restrict__ dst, int* __restrict__ deg) {
    int e = blockIdx.x * blockDim.x + threadIdx.x;
    if (e < N_EDGES) atomicAdd(&deg[dst[e]], 1);
}

__global__ void scan_kernel(const int* __restrict__ deg, int* __restrict__ row_ptr) {
    __shared__ int part[1024];
    const int PER = 20;
    int t = threadIdx.x;
    int base = t * PER;
    int vals[PER];
    int s = 0;
    #pragma unroll
    for (int i = 0; i < PER; ++i) {
        int idx = base + i;
        int v = (idx < N_NODES) ? deg[idx] : 0;
        vals[i] = s; s += v;
    }
    part[t] = s;
    __syncthreads();
    for (int off = 1; off < 1024; off <<= 1) {
        int v = (t >= off) ? part[t - off] : 0;
        __syncthreads();
        part[t] += v;
        __syncthreads();
    }
    int pre = (t == 0) ? 0 : part[t - 1];
    #pragma unroll
    for (int i = 0; i < PER; ++i) {
        int idx = base + i;
        if (idx < N_NODES) row_ptr[idx] = pre + vals[i];
    }
    if (t == 0) row_ptr[N_NODES] = N_EDGES;
}

__global__ void cursor_copy(const int* __restrict__ row_ptr, int* __restrict__ cur) {
    int i = blockIdx.x * blockDim.x + threadIdx.x;
    if (i < N_NODES) cur[i] = row_ptr[i];
}

__global__ void fill_kernel(const int* __restrict__ src, const int* __restrict__ dst,
                            int* __restrict__ cur, int* __restrict__ colx) {
    int e = blockIdx.x * blockDim.x + threadIdx.x;
    if (e >= N_EDGES) return;
    int d = dst[e];
    int p = atomicAdd(&cur[d], 1);
    colx[p] = src[e];
}

// ---- WcombT[r][gn] = sum_c W[r][c]*wih[gn][c]; swizzled fp16 hi/lo --------
__launch_bounds__(256)
__global__ void wcomb_split(const float* __restrict__ W1, const float* __restrict__ W2,
                            const float* __restrict__ wih1, const float* __restrict__ wih2,
                            _Float16* __restrict__ whi, _Float16* __restrict__ wlo) {
    int z = blockIdx.z, layer = z >> 3, step = z & 7;
    const float* A  = (layer ? W2 : W1) + (size_t)step * C * C;  // [r][c]
    const float* Bm = layer ? wih2 : wih1;                       // [gn][c]
    _Float16* ohi = whi + (size_t)z * WSTEP;
    _Float16* olo = wlo + (size_t)z * WSTEP;
    __shared__ float As[16][68];
    __shared__ float Bs[16][68];
    int tid = threadIdx.x;
    int tx = tid & 15, ty = tid >> 4;
    int rowBase = blockIdx.y * 64, colBase = blockIdx.x * 64;
    float acc[4][4] = {};
    int lr = tid >> 2, k4 = (tid & 3) * 4;
    for (int k0 = 0; k0 < C; k0 += 16) {
        {
            int gr = rowBase + lr;
            int gn = colBase + lr;
            #pragma unroll
            for (int j = 0; j < 4; ++j) {
                int k = k0 + k4 + j;
                As[k4 + j][lr] = (gr < C && k < C) ? A[(size_t)gr * C + k] : 0.f;
                Bs[k4 + j][lr] = (gn < 3 * C && k < C) ? Bm[(size_t)gn * C + k] : 0.f;
            }
        }
        __syncthreads();
        #pragma unroll
        for (int k = 0; k < 16; ++k) {
            float4 a = *(const float4*)&As[k][ty * 4];
            float4 b = *(const float4*)&Bs[k][tx * 4];
            float av[4] = {a.x, a.y, a.z, a.w};
            float bv[4] = {b.x, b.y, b.z, b.w};
            #pragma unroll
            for (int i = 0; i < 4; ++i)
                #pragma unroll
                for (int j = 0; j < 4; ++j)
                    acc[i][j] += av[i] * bv[j];
        }
        __syncthreads();
    }
    #pragma unroll
    for (int i = 0; i < 4; ++i) {
        int r = rowBase + ty * 4 + i;
        if (r >= C) continue;
        #pragma unroll
        for (int j = 0; j < 4; ++j) {
            int gn = colBase + tx * 4 + j;
            if (gn >= 3 * C) continue;
            int g = (gn >= 2 * C) ? 2 : ((gn >= C) ? 1 : 0);
            int n = gn - g * C;
            size_t idx = (((size_t)g * 40 + (r >> 3)) * NPAD + n) * 8 + (r & 7);
            _Float16 hi, lo; split16(acc[i][j], hi, lo);
            ohi[idx] = hi; olo[idx] = lo;
        }
    }
}

// ---- whh^T swizzle + split: B[k][gn] = whh[gn][k], fp16 hi/lo ----
__global__ void whh_split(const float* __restrict__ whh1, const float* __restrict__ whh2,
                          _Float16* __restrict__ whi, _Float16* __restrict__ wlo) {
    int idx = blockIdx.x * blockDim.x + threadIdx.x;
    if (idx >= 2 * 3 * C * C) return;
    int k = idx % C;
    int rest = idx / C;
    int gn = rest % (3 * C);
    int layer = rest / (3 * C);
    int g = (gn >= 2 * C) ? 2 : ((gn >= C) ? 1 : 0);
    int n = gn - g * C;
    float v = (layer ? whh2 : whh1)[(size_t)gn * C + k];
    size_t o = (size_t)layer * WSTEP + (((size_t)g * 40 + (k >> 3)) * NPAD + n) * 8 + (k & 7);
    _Float16 hi, lo; split16(v, hi, lo);
    whi[o] = hi; wlo[o] = lo;
}

// ---- CSR gather from fp32 h -> exact fp16 hi/lo split agg [N x KP] ----
__global__ void aggregate_kernel(const float* __restrict__ h,
                                 const int* __restrict__ rowp,
                                 const int* __restrict__ colx,
                                 _Float16* __restrict__ agh, _Float16* __restrict__ agl) {
    const int node = blockIdx.x * 4 + (threadIdx.x >> 6);
    const int lane = threadIdx.x & 63;
    const int beg = rowp[node], end = rowp[node + 1];
    float4 a0 = make_float4(0.f, 0.f, 0.f, 0.f);
    float4 a1 = make_float4(0.f, 0.f, 0.f, 0.f);
    const bool tail = lane < 11;       // chunks 64..74 cover cols 256..299
    for (int e = beg; e < end; ++e) {
        const float* row = h + (size_t)colx[e] * C;
        float4 v = *(const float4*)&row[lane * 4];
        a0.x += v.x; a0.y += v.y; a0.z += v.z; a0.w += v.w;
        if (tail) {
            float4 u = *(const float4*)&row[(64 + lane) * 4];
            a1.x += u.x; a1.y += u.y; a1.z += u.z; a1.w += u.w;
        }
    }
    half4 vh, vl;
    {
        _Float16 hi, lo;
        split16(a0.x, hi, lo); vh[0] = hi; vl[0] = lo;
        split16(a0.y, hi, lo); vh[1] = hi; vl[1] = lo;
        split16(a0.z, hi, lo); vh[2] = hi; vl[2] = lo;
        split16(a0.w, hi, lo); vh[3] = hi; vl[3] = lo;
    }
    _Float16* oh = agh + (size_t)node * KP;
    _Float16* ol = agl + (size_t)node * KP;
    *(half4*)&oh[lane * 4] = vh;
    *(half4*)&ol[lane * 4] = vl;
    if (tail) {
        _Float16 hi, lo;
        split16(a1.x, hi, lo); vh[0] = hi; vl[0] = lo;
        split16(a1.y, hi, lo); vh[1] = hi; vl[1] = lo;
        split16(a1.z, hi, lo); vh[2] = hi; vl[2] = lo;
        split16(a1.w, hi, lo); vh[3] = hi; vl[3] = lo;
        *(half4*)&oh[(64 + lane) * 4] = vh;
        *(half4*)&ol[(64 + lane) * 4] = vl;
    }
}

// 3 MFMAs per logical product: a1 += XH*BH; a2 += XH*BL + XL*BH
#define MFMA_TRIPLE(A1, A2, XH, XL, BH, BL)                                   \
    A1 = __builtin_amdgcn_mfma_f32_16x16x32_f16(XH, BH, A1, 0, 0, 0);         \
    A2 = __builtin_amdgcn_mfma_f32_16x16x32_f16(XH, BL, A2, 0, 0, 0);         \
    A2 = __builtin_amdgcn_mfma_f32_16x16x32_f16(XL, BH, A2, 0, 0, 0);

// ---- fused MFMA GRU step, v6 = v5 sync structure + PING-PONG fp16 state ----
// R4 failure root cause: the dim3(313,2) column split races on hh/hl --
// every block needs the FULL old h-row for the h*whh^T A-operand, but the
// sibling column-block writes new hh/hl for its columns in its epilogue.
// Fix: gru reads hh_in/hl_in and writes hh_out/hl_out (host swaps per step).
// h (fp32) has no such hazard: each block reads/writes only its own columns.
// Sync schedule unchanged from v5 (triple-buffered B, vmcnt(3) counted,
// one s_barrier per phase, STAGE issued after the barrier into the buffer
// whose readers all passed it).  LDS = 84KB A + 72KB B = 154KB.
__launch_bounds__(512, 2)
__global__ void gru_f16(const _Float16* __restrict__ hh_in, const _Float16* __restrict__ hl_in,
                        _Float16* __restrict__ hh_out, _Float16* __restrict__ hl_out,
                        const _Float16* __restrict__ agh, const _Float16* __restrict__ agl,
                        const _Float16* __restrict__ wch, const _Float16* __restrict__ wcl,
                        const _Float16* __restrict__ whh_, const _Float16* __restrict__ whl_,
                        const float* __restrict__ bih, const float* __restrict__ bhh,
                        float* __restrict__ h) {
    __shared__ _Float16 Lhh[64 * SP];
    __shared__ _Float16 Lhl[64 * SP];
    __shared__ _Float16 LB[3 * LBH];
    const int tid = threadIdx.x;
    const int rowBase = blockIdx.x * 64;       // 313 row-tiles; last partial
    const int cbase = blockIdx.y * 5;          // ct-pair half: c in [cbase, cbase+5)
    // ---- stage hh/hl (64 rows, row-clamped) from the INPUT buffers ----
    {
        int r = tid >> 3, c8 = tid & 7;
        int gr = rowBase + r; if (gr > N_NODES - 1) gr = N_NODES - 1;
        const _Float16* ph = hh_in + (size_t)gr * KP;
        const _Float16* pl = hl_in + (size_t)gr * KP;
        #pragma unroll
        for (int i = 0; i < 5; ++i) {
            int k = (c8 + i * 8) * 8;
            *(int4*)&Lhh[r * SP + k] = *(const int4*)&ph[k];
            *(int4*)&Lhl[r * SP + k] = *(const int4*)&pl[k];
        }
    }
    const int lane = tid & 63, w = tid >> 6;
    const int quad = lane >> 4, n15 = lane & 15;
    const int rw = w & 3, cnw = w >> 2;
    const int arow = rw * 16 + n15;
    // ---- G (agg hi/lo) fragments in registers: 16 rows, all 10 kt ----
    half8 gh_[10], gl_[10];
    {
        int gr = rowBase + arow; if (gr > N_NODES - 1) gr = N_NODES - 1;
        const _Float16* pg = agh + (size_t)gr * KP + quad * 8;
        const _Float16* pl2 = agl + (size_t)gr * KP + quad * 8;
        #pragma unroll
        for (int kt = 0; kt < 10; ++kt) {
            gh_[kt] = *(const half8*)&pg[kt * 32];
            gl_[kt] = *(const half8*)&pl2[kt * 32];
        }
    }
    // ---- stage-slot precompute: slot s = tid + i*512 ->
    //      s = ((cn*12 + mat)*4 + kc)*16 + n15  (half ofs s*8, lane-linear)
    const _Float16* gbs[3];
    int kcs[3], n15s[3], cns[3];
    #pragma unroll
    for (int i = 0; i < 3; ++i) {
        int s = tid + i * 512;
        n15s[i] = s & 15;
        kcs[i] = (s >> 4) & 3;
        int mc = s >> 6;                     // 0..23
        int mat = (mc >= 12) ? (mc - 12) : mc;
        cns[i] = (mc >= 12) ? 1 : 0;
        int arrs = mat / 3, gate = mat - arrs * 3;
        const _Float16* base = (arrs == 0) ? wch : (arrs == 1) ? wcl
                             : (arrs == 2) ? whh_ : whl_;
        gbs[i] = base + (size_t)gate * GOFS;
    }
    _Float16* ldsb = &LB[w * 512];           // + buf*LBH + i*4096 (+ lane*8 by HW)
    auto STAGE = [&](int c2, int kt2, int buf) {
        #pragma unroll
        for (int i = 0; i < 3; ++i) {
            int ct = c2 * 2 + cns[i]; if (ct > 18) ct = 18;
            int col = ct * 16 + n15s[i];
            const _Float16* src = gbs[i] + ((size_t)((kt2 * 4 + kcs[i]) * NPAD + col)) * 8;
            __builtin_amdgcn_global_load_lds(
                (const __attribute__((address_space(1))) void*)src,
                (__attribute__((address_space(3))) void*)(ldsb + buf * LBH + i * 4096),
                16, 0, 0);
        }
    };
    // prologue: A in LDS published; B phases 0,1 staged (drained once here)
    STAGE(cbase, 0, 0);
    STAGE(cbase, 1, 1);
    __syncthreads();
    const _Float16* bb = &LB[cnw * 6144 + quad * 128 + n15 * 8];
    const int aofs = arow * SP + quad * 8;
    int bufc = 0, bufs = 2;                  // compute buf = p%3, stage buf = (p+2)%3

    for (int cc = cbase; cc < cbase + 5; ++cc) {
        const bool tail_c = (cc == cbase + 4);
        floatx4 a1[6], a2[6];
        #pragma unroll
        for (int g = 0; g < 6; ++g) {
            a1[g] = (floatx4){0.f, 0.f, 0.f, 0.f};
            a2[g] = (floatx4){0.f, 0.f, 0.f, 0.f};
        }
        #pragma unroll
        for (int kt = 0; kt < 10; ++kt) {
            // own loads for phase p retired -> barrier publishes all writes
            if (tail_c && kt == 9) { asm volatile("s_waitcnt vmcnt(0)" ::: "memory"); }
            else                   { asm volatile("s_waitcnt vmcnt(3)" ::: "memory"); }
            __builtin_amdgcn_s_barrier();
            // stage phase p+2 (safe: its buffer's readers all passed this barrier)
            if (!(tail_c && kt >= 8)) {
                int kt2 = kt + 2, c2 = cc;
                if (kt2 >= 10) { kt2 -= 10; ++c2; }
                STAGE(c2, kt2, bufs);
            }
            __builtin_amdgcn_sched_barrier(0);
            const _Float16* bbk = bb + bufc * LBH;
            half8 b0  = *(const half8*)&bbk[0 * 512];
            half8 b1  = *(const half8*)&bbk[1 * 512];
            half8 b2  = *(const half8*)&bbk[2 * 512];
            half8 b3  = *(const half8*)&bbk[3 * 512];
            half8 b4  = *(const half8*)&bbk[4 * 512];
            half8 b5  = *(const half8*)&bbk[5 * 512];
            half8 b6  = *(const half8*)&bbk[6 * 512];
            half8 b7  = *(const half8*)&bbk[7 * 512];
            half8 b8  = *(const half8*)&bbk[8 * 512];
            half8 b9  = *(const half8*)&bbk[9 * 512];
            half8 b10 = *(const half8*)&bbk[10 * 512];
            half8 b11 = *(const half8*)&bbk[11 * 512];
            half8 AH = *(const half8*)&Lhh[aofs + kt * 32];
            half8 AL = *(const half8*)&Lhl[aofs + kt * 32];
            const half8 GH = gh_[kt], GL = gl_[kt];
            __builtin_amdgcn_s_setprio(1);
            MFMA_TRIPLE(a1[0], a2[0], GH, GL, b0, b3)
            MFMA_TRIPLE(a1[1], a2[1], GH, GL, b1, b4)
            MFMA_TRIPLE(a1[2], a2[2], GH, GL, b2, b5)
            MFMA_TRIPLE(a1[3], a2[3], AH, AL, b6, b9)
            MFMA_TRIPLE(a1[4], a2[4], AH, AL, b7, b10)
            MFMA_TRIPLE(a1[5], a2[5], AH, AL, b8, b11)
            __builtin_amdgcn_s_setprio(0);
            bufc = (bufc == 2) ? 0 : bufc + 1;
            bufs = (bufs == 2) ? 0 : bufs + 1;
        }
        // ---- epilogue for this ct (skip ghost ct=19 duplicate) ----
        const int ct = cc * 2 + cnw;
        if (ct <= 18) {
            const int col = ct * 16 + n15;
            if (col < C) {
                const float invS = 1.0f / LOSCALE;
                const float br = bih[col], bz = bih[C + col], bn = bih[2 * C + col];
                const float cr = bhh[col], cz = bhh[C + col], cq = bhh[2 * C + col];
                #pragma unroll
                for (int i = 0; i < 4; ++i) {
                    int grow = rowBase + rw * 16 + quad * 4 + i;
                    if (grow < N_NODES) {
                        float ir  = a1[0][i] + a2[0][i] * invS + br;
                        float iz  = a1[1][i] + a2[1][i] * invS + bz;
                        float inn = a1[2][i] + a2[2][i] * invS + bn;
                        float hr  = a1[3][i] + a2[3][i] * invS + cr;
                        float hz  = a1[4][i] + a2[4][i] * invS + cz;
                        float hn  = a1[5][i] + a2[5][i] * invS + cq;
                        float r = 1.f / (1.f + __expf(-(ir + hr)));
                        float z = 1.f / (1.f + __expf(-(iz + hz)));
                        float nn = tanhf(inn + r * hn);
                        float hold = h[(size_t)grow * C + col];
                        float hnew = (1.f - z) * nn + z * hold;
                        h[(size_t)grow * C + col] = hnew;
                        _Float16 nh, nl; split16(hnew, nh, nl);
                        hh_out[(size_t)grow * KP + col] = nh;
                        hl_out[(size_t)grow * KP + col] = nl;
                    }
                }
            }
        }
    }
}

// ---------------- relu (h fp32 + hh/hl fp16) ----------------
__global__ void relu_kernel(float* __restrict__ h, _Float16* __restrict__ hh,
                            _Float16* __restrict__ hl) {
    int idx = blockIdx.x * blockDim.x + threadIdx.x;
    if (idx >= N_NODES * C) return;
    int n = idx / C, c = idx - n * C;
    float v = fmaxf(h[idx], 0.f);
    h[idx] = v;
    _Float16 hi, lo; split16(v, hi, lo);
    hh[(size_t)n * KP + c] = hi;
    hl[(size_t)n * KP + c] = lo;
}

// ---------------- mean pool ----------------
__global__ void pool_kernel(const float* __restrict__ h, float* __restrict__ pooled) {
    int c = threadIdx.x;
    if (c >= C) return;
    float acc = 0.f;
    for (int n = blockIdx.x; n < N_NODES; n += gridDim.x)
        acc += h[(size_t)n * C + c];
    atomicAdd(&pooled[c], acc);
}

// ---------------- log_softmax ----------------
__global__ void lsm_kernel(const float* __restrict__ pooled, float* __restrict__ out) {
    __shared__ float sm[512];
    int t = threadIdx.x;
    float v = (t < C) ? pooled[t] * (1.0f / N_NODES) : -INFINITY;
    sm[t] = v;
    __syncthreads();
    for (int s = 256; s > 0; s >>= 1) {
        if (t < s) sm[t] = fmaxf(sm[t], sm[t + s]);
        __syncthreads();
    }
    float mx = sm[0];
    __syncthreads();
    float e = (t < C) ? expf(v - mx) : 0.f;
    sm[t] = e;
    __syncthreads();
    for (int s = 256; s > 0; s >>= 1) {
        if (t < s) sm[t] += sm[t + s];
        __syncthreads();
    }
    float lse = logf(sm[0]);
    if (t < C) out[t] = (v - mx) - lse;
}

extern "C" void kernel_launch(void* const* d_in, const int* in_sizes, int n_in,
                              void* d_out, int out_size, void* d_ws, size_t ws_size,
                              hipStream_t stream) {
    const float* x      = (const float*)d_in[0];
    const int*   ei     = (const int*)d_in[1];
    const int*   src    = ei;
    const int*   dst    = ei + N_EDGES;
    const float* W1     = (const float*)d_in[2];
    const float* g1_wih = (const float*)d_in[3];
    const float* g1_whh = (const float*)d_in[4];
    const float* g1_bih = (const float*)d_in[5];
    const float* g1_bhh = (const float*)d_in[6];
    const float* W2     = (const float*)d_in[7];
    const float* g2_wih = (const float*)d_in[8];
    const float* g2_whh = (const float*)d_in[9];
    const float* g2_bih = (const float*)d_in[10];
    const float* g2_bhh = (const float*)d_in[11];

    char* p = (char*)d_ws;
    float* h = (float*)p;               p += (size_t)N_NODES * C * 4;    // 24.0 MB
    _Float16* hhA = (_Float16*)p;       p += (size_t)N_NODES * KP * 2;   // 12.8 MB
    _Float16* hlA = (_Float16*)p;       p += (size_t)N_NODES * KP * 2;   // 12.8 MB
    _Float16* hhB = (_Float16*)p;       p += (size_t)N_NODES * KP * 2;   // 12.8 MB
    _Float16* hlB = (_Float16*)p;       p += (size_t)N_NODES * KP * 2;   // 12.8 MB
    _Float16* agh = (_Float16*)p;       p += (size_t)N_NODES * KP * 2;   // 12.8 MB
    _Float16* agl = (_Float16*)p;       p += (size_t)N_NODES * KP * 2;   // 12.8 MB
    _Float16* wch = (_Float16*)p;       p += (size_t)16 * WSTEP * 2;     //  9.34 MB
    _Float16* wcl = (_Float16*)p;       p += (size_t)16 * WSTEP * 2;     //  9.34 MB
    _Float16* wh_hi = (_Float16*)p;     p += (size_t)2 * WSTEP * 2;      //  1.17 MB
    _Float16* wh_lo = (_Float16*)p;     p += (size_t)2 * WSTEP * 2;      //  1.17 MB
    float* pooled = (float*)p;          p += 1216;
    int* row_ptr = (int*)p;             p += 80016;
    int* colx = (int*)p;                p += (size_t)N_EDGES * 4;        //  1.28 MB
    int* deg = (int*)p;                 p += 80000;
    int* cursor = (int*)p;              p += 80000;

    hipMemsetAsync(deg, 0, N_NODES * sizeof(int), stream);
    hipMemsetAsync(hhB, 0, (size_t)N_NODES * KP * 2, stream);   // pad cols must be 0
    hipMemsetAsync(hlB, 0, (size_t)N_NODES * KP * 2, stream);
    hipMemsetAsync(agh, 0, (size_t)N_NODES * KP * 2, stream);
    hipMemsetAsync(agl, 0, (size_t)N_NODES * KP * 2, stream);
    hipMemsetAsync(wch, 0, (size_t)16 * WSTEP * 2, stream);
    hipMemsetAsync(wcl, 0, (size_t)16 * WSTEP * 2, stream);
    hipMemsetAsync(wh_hi, 0, (size_t)2 * WSTEP * 2, stream);
    hipMemsetAsync(wh_lo, 0, (size_t)2 * WSTEP * 2, stream);
    hipMemsetAsync(pooled, 0, C * sizeof(float), stream);

    pad_kernel<<<(N_NODES * KP + 255) / 256, 256, 0, stream>>>(x, h, hhA, hlA);

    hist_kernel<<<(N_EDGES + 255) / 256, 256, 0, stream>>>(dst, deg);
    scan_kernel<<<1, 1024, 0, stream>>>(deg, row_ptr);
    cursor_copy<<<(N_NODES + 255) / 256, 256, 0, stream>>>(row_ptr, cursor);
    fill_kernel<<<(N_EDGES + 255) / 256, 256, 0, stream>>>(src, dst, cursor, colx);

    wcomb_split<<<dim3(15, 5, 16), 256, 0, stream>>>(W1, W2, g1_wih, g2_wih, wch, wcl);
    whh_split<<<(2 * 3 * C * C + 255) / 256, 256, 0, stream>>>(g1_whh, g2_whh, wh_hi, wh_lo);

    _Float16* hh_cur = hhA; _Float16* hl_cur = hlA;
    _Float16* hh_alt = hhB; _Float16* hl_alt = hlB;
    for (int layer = 0; layer < 2; ++layer) {
        const float* bih = layer ? g2_bih : g1_bih;
        const float* bhh = layer ? g2_bhh : g1_bhh;
        const _Float16* whh_hi = wh_hi + (size_t)layer * WSTEP;
        const _Float16* whh_lo = wh_lo + (size_t)layer * WSTEP;
        for (int step = 0; step < L_STEPS; ++step) {
            const _Float16* wc_hi = wch + (size_t)(layer * 8 + step) * WSTEP;
            const _Float16* wc_lo = wcl + (size_t)(layer * 8 + step) * WSTEP;
            aggregate_kernel<<<N_NODES / 4, 256, 0, stream>>>(h, row_ptr, colx, agh, agl);
            gru_f16<<<dim3(313, 2), 512, 0, stream>>>(
                hh_cur, hl_cur, hh_alt, hl_alt, agh, agl,
                wc_hi, wc_lo, whh_hi, whh_lo, bih, bhh, h);
            { _Float16* t;
              t = hh_cur; hh_cur = hh_alt; hh_alt = t;
              t = hl_cur; hl_cur = hl_alt; hl_alt = t; }
        }
        if (layer == 0)
            relu_kernel<<<(N_NODES * C + 255) / 256, 256, 0, stream>>>(h, hh_cur, hl_cur);
    }

    pool_kernel<<<256, 320, 0, stream>>>(h, pooled);
    lsm_kernel<<<1, 512, 0, stream>>>(pooled, (float*)d_out);
}